// Round 1
// baseline (159.618 us; speedup 1.0000x reference)
//
#include <hip/hip_runtime.h>
#include <hip/hip_bf16.h>
#include <math.h>

#define NSLICES 1024
#define DIM     768
#define NPTS    256
#define K_REF   17

// ws layout (in floats)
#define ACC_INV 0
#define ACC_SIG 1
#define NORM_OFF 16
#define XA_OFF  (NORM_OFF + NSLICES)            // 1040
#define XB_OFF  (XA_OFF + NSLICES * NPTS)       // 1040 + 262144

__device__ __forceinline__ float block_reduce_256(float v, float* red, int tid) {
    red[tid] = v;
    for (int s = 128; s > 0; s >>= 1) {
        __syncthreads();
        if (tid < s) red[tid] += red[tid + s];
    }
    __syncthreads();
    return red[0];
}

// ---------------- inv_loss: sum (za-zb)^2 ----------------
__global__ void inv_kernel(const float* __restrict__ za, const float* __restrict__ zb,
                           float* __restrict__ w) {
    __shared__ float red[256];
    int tid = threadIdx.x;
    int idx = blockIdx.x * blockDim.x + tid;
    const int n = NPTS * DIM;
    float p = 0.f;
    for (int i = idx; i < n; i += gridDim.x * blockDim.x) {
        float d = za[i] - zb[i];
        p += d * d;
    }
    float s = block_reduce_256(p, red, tid);
    if (tid == 0) atomicAdd(&w[ACC_INV], s);
}

// ---------------- per-slice inverse norms ----------------
__global__ void norm_kernel(const float* __restrict__ slices, float* __restrict__ w) {
    __shared__ float red[256];
    int m = blockIdx.x;
    int tid = threadIdx.x;
    const float* row = slices + (size_t)m * DIM;
    float p = 0.f;
    for (int d = tid; d < DIM; d += 256) {
        float v = row[d];
        p += v * v;
    }
    float s = block_reduce_256(p, red, tid);
    if (tid == 0) {
        float nrm = sqrtf(s);
        w[NORM_OFF + m] = 1.0f / fmaxf(nrm, 1e-12f);
    }
}

// ---------------- projection GEMM: x[m][n] = inv_norm[m] * dot(slices[m], z[n]) ----
// grid: (N/64, M/64, 2), block 256 threads = 16x16, each thread 4x4 outputs.
__global__ __launch_bounds__(256) void proj_kernel(const float* __restrict__ za,
                                                   const float* __restrict__ zb,
                                                   const float* __restrict__ slices,
                                                   float* __restrict__ w) {
    __shared__ float sA[64][17];
    __shared__ float sB[64][17];
    const int nt = blockIdx.x;           // 0..3
    const int mt = blockIdx.y;           // 0..15
    const int zi = blockIdx.z;           // 0..1
    const float* Z = zi ? zb : za;
    float* X = w + (zi ? XB_OFF : XA_OFF);
    const int m0 = mt * 64, n0 = nt * 64;
    const int tid = threadIdx.x;
    const int tx = tid & 15, ty = tid >> 4;
    const int lr = tid >> 2, lq = tid & 3;   // loader: row 0..63, quad 0..3

    float acc[4][4] = {};

    for (int k0 = 0; k0 < DIM; k0 += 16) {
        float4 av = *(const float4*)(slices + (size_t)(m0 + lr) * DIM + k0 + lq * 4);
        float4 bv = *(const float4*)(Z + (size_t)(n0 + lr) * DIM + k0 + lq * 4);
        sA[lr][lq * 4 + 0] = av.x; sA[lr][lq * 4 + 1] = av.y;
        sA[lr][lq * 4 + 2] = av.z; sA[lr][lq * 4 + 3] = av.w;
        sB[lr][lq * 4 + 0] = bv.x; sB[lr][lq * 4 + 1] = bv.y;
        sB[lr][lq * 4 + 2] = bv.z; sB[lr][lq * 4 + 3] = bv.w;
        __syncthreads();
#pragma unroll
        for (int kk = 0; kk < 16; ++kk) {
            float a0 = sA[ty * 4 + 0][kk];
            float a1 = sA[ty * 4 + 1][kk];
            float a2 = sA[ty * 4 + 2][kk];
            float a3 = sA[ty * 4 + 3][kk];
            float b0 = sB[tx * 4 + 0][kk];
            float b1 = sB[tx * 4 + 1][kk];
            float b2 = sB[tx * 4 + 2][kk];
            float b3 = sB[tx * 4 + 3][kk];
            acc[0][0] += a0 * b0; acc[0][1] += a0 * b1; acc[0][2] += a0 * b2; acc[0][3] += a0 * b3;
            acc[1][0] += a1 * b0; acc[1][1] += a1 * b1; acc[1][2] += a1 * b2; acc[1][3] += a1 * b3;
            acc[2][0] += a2 * b0; acc[2][1] += a2 * b1; acc[2][2] += a2 * b2; acc[2][3] += a2 * b3;
            acc[3][0] += a3 * b0; acc[3][1] += a3 * b1; acc[3][2] += a3 * b2; acc[3][3] += a3 * b3;
        }
        __syncthreads();
    }

#pragma unroll
    for (int i = 0; i < 4; ++i) {
        int m = m0 + ty * 4 + i;
        float inorm = w[NORM_OFF + m];
        float4 o;
        o.x = acc[i][0] * inorm;
        o.y = acc[i][1] * inorm;
        o.z = acc[i][2] * inorm;
        o.w = acc[i][3] * inorm;
        *(float4*)(X + (size_t)m * NPTS + n0 + tx * 4) = o;
    }
}

// ---------------- per-slice sigreg (t1 + t2), accumulate scaled ----------------
// grid: (NSLICES, 2); block 256 threads (one per sample point).
__global__ __launch_bounds__(256) void sigreg_kernel(float* __restrict__ w) {
    __shared__ float red[256];
    __shared__ float xs[256];
    __shared__ float gs[K_REF];
    const int m = blockIdx.x;
    const int zi = blockIdx.y;
    const float* x = w + (zi ? XB_OFF : XA_OFF) + (size_t)m * NPTS;
    const int tid = threadIdx.x;

    float xv = x[tid];
    float mu = block_reduce_256(xv, red, tid) * (1.0f / NPTS);
    __syncthreads();   // everyone has read red[0]
    float dv = xv - mu;
    float ss = block_reduce_256(dv * dv, red, tid);
    float sd = sqrtf(ss * (1.0f / (NPTS - 1))) + 1e-6f;
    float xsv = dv / sd;
    xs[tid] = xsv;
    if (tid < K_REF) {
        float q = 0.01f + 0.06125f * (float)tid;
        gs[tid] = erfinvf(2.0f * q - 1.0f) * 1.41421356237309504880f;
    }
    __syncthreads();

    float s1 = 0.f;
#pragma unroll 8
    for (int j = 0; j < NPTS; ++j) {
        float dd = xsv - xs[j];
        s1 += __expf(-0.5f * dd * dd);
    }
    float s2 = 0.f;
#pragma unroll
    for (int k = 0; k < K_REF; ++k) {
        float dd = xsv - gs[k];
        s2 += __expf(-0.5f * dd * dd);
    }
    float c = s1 * (1.0f / ((float)NPTS * (float)NPTS))
            - s2 * (2.0f / ((float)NPTS * (float)K_REF));
    __syncthreads();   // done reading xs/red
    float tot = block_reduce_256(c, red, tid);
    if (tid == 0) atomicAdd(&w[ACC_SIG], tot * (0.5f / (float)NSLICES));
}

// ---------------- final: t3 + combine ----------------
__global__ void final_kernel(const float* __restrict__ w, float* __restrict__ out) {
    if (threadIdx.x == 0 && blockIdx.x == 0) {
        float g[K_REF];
#pragma unroll
        for (int k = 0; k < K_REF; ++k) {
            float q = 0.01f + 0.06125f * (float)k;
            g[k] = erfinvf(2.0f * q - 1.0f) * 1.41421356237309504880f;
        }
        float t3 = 0.f;
        for (int k = 0; k < K_REF; ++k)
            for (int l = 0; l < K_REF; ++l) {
                float dd = g[k] - g[l];
                t3 += __expf(-0.5f * dd * dd);
            }
        t3 *= (1.0f / ((float)K_REF * (float)K_REF));
        float inv = w[ACC_INV] * (1.0f / ((float)NPTS * (float)DIM));
        out[0] = 25.0f * inv + 25.0f * (w[ACC_SIG] + t3);
    }
}

extern "C" void kernel_launch(void* const* d_in, const int* in_sizes, int n_in,
                              void* d_out, int out_size, void* d_ws, size_t ws_size,
                              hipStream_t stream) {
    const float* za = (const float*)d_in[0];
    const float* zb = (const float*)d_in[1];
    const float* slices = (const float*)d_in[2];
    float* out = (float*)d_out;
    float* w = (float*)d_ws;

    // zero the accumulators (ws is re-poisoned to 0xAA before every launch)
    hipMemsetAsync(d_ws, 0, 64, stream);

    inv_kernel<<<192, 256, 0, stream>>>(za, zb, w);
    norm_kernel<<<NSLICES, 256, 0, stream>>>(slices, w);
    dim3 pg(4, 16, 2);
    proj_kernel<<<pg, 256, 0, stream>>>(za, zb, slices, w);
    dim3 sg(NSLICES, 2);
    sigreg_kernel<<<sg, 256, 0, stream>>>(w);
    final_kernel<<<1, 64, 0, stream>>>(w, out);
}

// Round 2
// 127.908 us; speedup vs baseline: 1.2479x; 1.2479x over previous
//
#include <hip/hip_runtime.h>
#include <hip/hip_bf16.h>
#include <math.h>

#define NSLICES 1024
#define DIM     768
#define NPTS    256
#define K_REF   17
#define KSPLIT  8
#define KCHUNK  (DIM / KSPLIT)      // 96
#define XSZ     (NSLICES * NPTS)    // 262144 floats per (z, kchunk) partial

// ws float layout
#define ACC_INV 0
#define ACC_SIG 1
#define XP_OFF  16

#if __has_builtin(__builtin_amdgcn_exp2f)
#define EXP2(x) __builtin_amdgcn_exp2f(x)
#else
#define EXP2(x) __expf((x) * 0.6931471805599453f)
#endif
#define NEG_HALF_LOG2E (-0.72134752044448170f)   // -0.5 * log2(e)

__device__ __forceinline__ float wave_sum(float v) {
#pragma unroll
    for (int o = 32; o; o >>= 1) v += __shfl_xor(v, o, 64);
    return v;
}

__device__ __forceinline__ float block_sum_256(float v, float* wred, int tid) {
    v = wave_sum(v);
    if ((tid & 63) == 0) wred[tid >> 6] = v;
    __syncthreads();
    float r = wred[0] + wred[1] + wred[2] + wred[3];
    __syncthreads();
    return r;
}

// ---------------- inv_loss: sum (za-zb)^2, float4, one elem per thread ------
__global__ __launch_bounds__(256) void inv_kernel(const float* __restrict__ za,
                                                  const float* __restrict__ zb,
                                                  float* __restrict__ w) {
    int idx = blockIdx.x * 256 + threadIdx.x;           // 192 blocks * 256 = 49152 float4s
    const float4* A = (const float4*)za;
    const float4* B = (const float4*)zb;
    float4 a = A[idx], b = B[idx];
    float dx = a.x - b.x, dy = a.y - b.y, dz = a.z - b.z, dw = a.w - b.w;
    float p = dx * dx + dy * dy + dz * dz + dw * dw;
    p = wave_sum(p);
    if ((threadIdx.x & 63) == 0) atomicAdd(&w[ACC_INV], p);
}

// ---------------- projection GEMM: x[m][n] = dot(slices[m], z[n]) -----------
// (slice normalization dropped: standardization is scale-invariant per slice)
// grid: (4 n-tiles, 16 m-tiles, 2 z * KSPLIT k-chunks), block 256 = 16x16, 4x4/thread.
// LDS transposed [kk][m] with pad so fragment reads are ds_read_b128.
__global__ __launch_bounds__(256) void proj_kernel(const float* __restrict__ za,
                                                   const float* __restrict__ zb,
                                                   const float* __restrict__ slices,
                                                   float* __restrict__ w, int npart) {
    __shared__ float sA[16][68];
    __shared__ float sB[16][68];
    const int nt = blockIdx.x;            // 0..3
    const int mt = blockIdx.y;            // 0..15
    const int zi = blockIdx.z >> 3;       // 0..1
    const int kc = blockIdx.z & 7;        // 0..7
    const float* Z = zi ? zb : za;
    const int m0 = mt * 64, n0 = nt * 64;
    const int tid = threadIdx.x;
    const int tx = tid & 15, ty = tid >> 4;
    const int lr = tid >> 2, lq = tid & 3;      // loader: row 0..63, quad 0..3
    const int kbase = kc * KCHUNK;

    float acc[4][4] = {};

    for (int k0 = 0; k0 < KCHUNK; k0 += 16) {
        float4 av = *(const float4*)(slices + (size_t)(m0 + lr) * DIM + kbase + k0 + lq * 4);
        float4 bv = *(const float4*)(Z + (size_t)(n0 + lr) * DIM + kbase + k0 + lq * 4);
        // transposed store: sA[kk][m]
        sA[lq * 4 + 0][lr] = av.x; sA[lq * 4 + 1][lr] = av.y;
        sA[lq * 4 + 2][lr] = av.z; sA[lq * 4 + 3][lr] = av.w;
        sB[lq * 4 + 0][lr] = bv.x; sB[lq * 4 + 1][lr] = bv.y;
        sB[lq * 4 + 2][lr] = bv.z; sB[lq * 4 + 3][lr] = bv.w;
        __syncthreads();
#pragma unroll
        for (int kk = 0; kk < 16; ++kk) {
            float4 a = *(const float4*)&sA[kk][ty * 4];
            float4 b = *(const float4*)&sB[kk][tx * 4];
            acc[0][0] += a.x * b.x; acc[0][1] += a.x * b.y; acc[0][2] += a.x * b.z; acc[0][3] += a.x * b.w;
            acc[1][0] += a.y * b.x; acc[1][1] += a.y * b.y; acc[1][2] += a.y * b.z; acc[1][3] += a.y * b.w;
            acc[2][0] += a.z * b.x; acc[2][1] += a.z * b.y; acc[2][2] += a.z * b.z; acc[2][3] += a.z * b.w;
            acc[3][0] += a.w * b.x; acc[3][1] += a.w * b.y; acc[3][2] += a.w * b.z; acc[3][3] += a.w * b.w;
        }
        __syncthreads();
    }

    if (npart == KSPLIT) {
        float* X = w + XP_OFF + ((size_t)zi * KSPLIT + kc) * XSZ;
#pragma unroll
        for (int i = 0; i < 4; ++i) {
            float4 o; o.x = acc[i][0]; o.y = acc[i][1]; o.z = acc[i][2]; o.w = acc[i][3];
            *(float4*)(X + (size_t)(m0 + ty * 4 + i) * NPTS + n0 + tx * 4) = o;
        }
    } else {
        float* X = w + XP_OFF + (size_t)zi * XSZ;
#pragma unroll
        for (int i = 0; i < 4; ++i)
#pragma unroll
            for (int j = 0; j < 4; ++j)
                atomicAdd(X + (size_t)(m0 + ty * 4 + i) * NPTS + n0 + tx * 4 + j, acc[i][j]);
    }
}

// ---------------- per-slice sigreg (t1 + t2) --------------------------------
// grid: (NSLICES, 2); block 256 (one thread per sample point).
__global__ __launch_bounds__(256) void sigreg_kernel(float* __restrict__ w, int npart) {
    __shared__ float xs[NPTS];
    __shared__ float gs[K_REF];
    __shared__ float wred[8];
    const int m = blockIdx.x;
    const int zi = blockIdx.y;
    const int tid = threadIdx.x;

    const float* Xb = w + XP_OFF + (size_t)zi * npart * XSZ + (size_t)m * NPTS + tid;
    float xv = 0.f;
    for (int p = 0; p < npart; ++p) xv += Xb[(size_t)p * XSZ];

    float mu = block_sum_256(xv, wred, tid) * (1.0f / NPTS);
    float dv = xv - mu;
    float ss = block_sum_256(dv * dv, wred, tid);
    float sd = sqrtf(ss * (1.0f / (NPTS - 1))) + 1e-6f;
    float xsv = dv / sd;
    xs[tid] = xsv;
    if (tid < K_REF) {
        float q = 0.01f + 0.06125f * (float)tid;
        gs[tid] = erfinvf(2.0f * q - 1.0f) * 1.41421356237309504880f;
    }
    __syncthreads();

    float s1a = 0.f, s1b = 0.f;
#pragma unroll 8
    for (int j = 0; j < NPTS; j += 2) {
        float d0 = xsv - xs[j];
        float d1 = xsv - xs[j + 1];
        s1a += EXP2(NEG_HALF_LOG2E * d0 * d0);
        s1b += EXP2(NEG_HALF_LOG2E * d1 * d1);
    }
    float s2 = 0.f;
#pragma unroll
    for (int k = 0; k < K_REF; ++k) {
        float d = xsv - gs[k];
        s2 += EXP2(NEG_HALF_LOG2E * d * d);
    }
    float c = (s1a + s1b) * (1.0f / ((float)NPTS * (float)NPTS))
            - s2 * (2.0f / ((float)NPTS * (float)K_REF));
    float tot = block_sum_256(c, wred, tid);
    if (tid == 0) atomicAdd(&w[ACC_SIG], tot * (0.5f / (float)NSLICES));
}

// ---------------- final: t3 + combine ---------------------------------------
__global__ void final_kernel(const float* __restrict__ w, float* __restrict__ out) {
    if (threadIdx.x == 0 && blockIdx.x == 0) {
        float g[K_REF];
#pragma unroll
        for (int k = 0; k < K_REF; ++k) {
            float q = 0.01f + 0.06125f * (float)k;
            g[k] = erfinvf(2.0f * q - 1.0f) * 1.41421356237309504880f;
        }
        float t3 = 0.f;
        for (int k = 0; k < K_REF; ++k)
            for (int l = 0; l < K_REF; ++l) {
                float dd = g[k] - g[l];
                t3 += EXP2(NEG_HALF_LOG2E * dd * dd);
            }
        t3 *= (1.0f / ((float)K_REF * (float)K_REF));
        float inv = w[ACC_INV] * (1.0f / ((float)NPTS * (float)DIM));
        out[0] = 25.0f * inv + 25.0f * (w[ACC_SIG] + t3);
    }
}

extern "C" void kernel_launch(void* const* d_in, const int* in_sizes, int n_in,
                              void* d_out, int out_size, void* d_ws, size_t ws_size,
                              hipStream_t stream) {
    const float* za = (const float*)d_in[0];
    const float* zb = (const float*)d_in[1];
    const float* slices = (const float*)d_in[2];
    float* out = (float*)d_out;
    float* w = (float*)d_ws;

    const size_t need_full = (size_t)(XP_OFF + 2 * KSPLIT * XSZ) * sizeof(float); // ~16.8 MB
    const int npart = (ws_size >= need_full) ? KSPLIT : 1;

    hipMemsetAsync(d_ws, 0, 64, stream);
    if (npart == 1)
        hipMemsetAsync(w + XP_OFF, 0, (size_t)2 * XSZ * sizeof(float), stream);

    inv_kernel<<<192, 256, 0, stream>>>(za, zb, w);
    dim3 pg(4, 16, 2 * KSPLIT);
    proj_kernel<<<pg, 256, 0, stream>>>(za, zb, slices, w, npart);
    dim3 sg(NSLICES, 2);
    sigreg_kernel<<<sg, 256, 0, stream>>>(w, npart);
    final_kernel<<<1, 64, 0, stream>>>(w, out);
}

// Round 3
// 110.692 us; speedup vs baseline: 1.4420x; 1.1555x over previous
//
#include <hip/hip_runtime.h>
#include <hip/hip_bf16.h>
#include <math.h>

#define NSLICES 1024
#define DIM     768
#define NPTS    256
#define K_REF   17
#define KSPLIT  8
#define KCHUNK  (DIM / KSPLIT)      // 96
#define XSZ     (NSLICES * NPTS)    // 262144 floats per (z, kchunk) partial

// ws float layout — every slot is fully rewritten every call (no zero-init needed)
#define INV_OFF 0                   // 192 partials
#define SIG_OFF 256                 // 2048 partials
#define XP_OFF  2560                // projection partials

#define NEG_HALF_LOG2E (-0.72134752044448170f)   // -0.5 * log2(e)
#define EXP2(x) __builtin_amdgcn_exp2f(x)

__device__ __forceinline__ float wave_sum(float v) {
#pragma unroll
    for (int o = 32; o; o >>= 1) v += __shfl_xor(v, o, 64);
    return v;
}

__device__ __forceinline__ float block_sum_256(float v, float* wred, int tid) {
    v = wave_sum(v);
    if ((tid & 63) == 0) wred[tid >> 6] = v;
    __syncthreads();
    float r = wred[0] + wred[1] + wred[2] + wred[3];
    __syncthreads();
    return r;
}

// ---------------- inv_loss partials: one slot per block ----------------------
__global__ __launch_bounds__(256) void inv_kernel(const float* __restrict__ za,
                                                  const float* __restrict__ zb,
                                                  float* __restrict__ w) {
    __shared__ float wred[4];
    int tid = threadIdx.x;
    int idx = blockIdx.x * 256 + tid;           // 192 blocks * 256 = 49152 float4s exactly
    const float4* A = (const float4*)za;
    const float4* B = (const float4*)zb;
    float4 a = A[idx], b = B[idx];
    float dx = a.x - b.x, dy = a.y - b.y, dz = a.z - b.z, dw = a.w - b.w;
    float p = dx * dx + dy * dy + dz * dz + dw * dw;
    float s = block_sum_256(p, wred, tid);
    if (tid == 0) w[INV_OFF + blockIdx.x] = s;
}

// ---------------- projection GEMM: x[m][n] = dot(slices[m], z[n]) -----------
// (slice normalization dropped: standardization is scale-invariant per slice)
// grid: (4 n-tiles, 16 m-tiles, 2 z * KSPLIT k-chunks), block 256 = 16x16, 4x4/thread.
__global__ __launch_bounds__(256) void proj_kernel(const float* __restrict__ za,
                                                   const float* __restrict__ zb,
                                                   const float* __restrict__ slices,
                                                   float* __restrict__ w, int npart) {
    __shared__ float sA[16][68];
    __shared__ float sB[16][68];
    const int nt = blockIdx.x;            // 0..3
    const int mt = blockIdx.y;            // 0..15
    const int zi = blockIdx.z >> 3;       // 0..1
    const int kc = blockIdx.z & 7;        // 0..7
    const float* Z = zi ? zb : za;
    const int m0 = mt * 64, n0 = nt * 64;
    const int tid = threadIdx.x;
    const int tx = tid & 15, ty = tid >> 4;
    const int lr = tid >> 2, lq = tid & 3;      // loader: row 0..63, quad 0..3
    const int kbase = kc * KCHUNK;

    float acc[4][4] = {};

    for (int k0 = 0; k0 < KCHUNK; k0 += 16) {
        float4 av = *(const float4*)(slices + (size_t)(m0 + lr) * DIM + kbase + k0 + lq * 4);
        float4 bv = *(const float4*)(Z + (size_t)(n0 + lr) * DIM + kbase + k0 + lq * 4);
        // transposed store: sA[kk][m]
        sA[lq * 4 + 0][lr] = av.x; sA[lq * 4 + 1][lr] = av.y;
        sA[lq * 4 + 2][lr] = av.z; sA[lq * 4 + 3][lr] = av.w;
        sB[lq * 4 + 0][lr] = bv.x; sB[lq * 4 + 1][lr] = bv.y;
        sB[lq * 4 + 2][lr] = bv.z; sB[lq * 4 + 3][lr] = bv.w;
        __syncthreads();
#pragma unroll
        for (int kk = 0; kk < 16; ++kk) {
            float4 a = *(const float4*)&sA[kk][ty * 4];
            float4 b = *(const float4*)&sB[kk][tx * 4];
            acc[0][0] += a.x * b.x; acc[0][1] += a.x * b.y; acc[0][2] += a.x * b.z; acc[0][3] += a.x * b.w;
            acc[1][0] += a.y * b.x; acc[1][1] += a.y * b.y; acc[1][2] += a.y * b.z; acc[1][3] += a.y * b.w;
            acc[2][0] += a.z * b.x; acc[2][1] += a.z * b.y; acc[2][2] += a.z * b.z; acc[2][3] += a.z * b.w;
            acc[3][0] += a.w * b.x; acc[3][1] += a.w * b.y; acc[3][2] += a.w * b.z; acc[3][3] += a.w * b.w;
        }
        __syncthreads();
    }

    if (npart == KSPLIT) {
        float* X = w + XP_OFF + ((size_t)zi * KSPLIT + kc) * XSZ;
#pragma unroll
        for (int i = 0; i < 4; ++i) {
            float4 o; o.x = acc[i][0]; o.y = acc[i][1]; o.z = acc[i][2]; o.w = acc[i][3];
            *(float4*)(X + (size_t)(m0 + ty * 4 + i) * NPTS + n0 + tx * 4) = o;
        }
    } else {
        float* X = w + XP_OFF + (size_t)zi * XSZ;
#pragma unroll
        for (int i = 0; i < 4; ++i)
#pragma unroll
            for (int j = 0; j < 4; ++j)
                atomicAdd(X + (size_t)(m0 + ty * 4 + i) * NPTS + n0 + tx * 4 + j, acc[i][j]);
    }
}

// ---------------- per-slice sigreg (t1 + t2), slot per block ----------------
// grid: (NSLICES, 2); block 256 (one thread per sample point).
__global__ __launch_bounds__(256) void sigreg_kernel(float* __restrict__ w, int npart) {
    __shared__ float xs[NPTS];
    __shared__ float gs[K_REF];
    __shared__ float wred[4];
    const int m = blockIdx.x;
    const int zi = blockIdx.y;
    const int tid = threadIdx.x;

    const float* Xb = w + XP_OFF + (size_t)zi * npart * XSZ + (size_t)m * NPTS + tid;
    float xv = 0.f;
    for (int p = 0; p < npart; ++p) xv += Xb[(size_t)p * XSZ];

    float mu = block_sum_256(xv, wred, tid) * (1.0f / NPTS);
    float dv = xv - mu;
    float ss = block_sum_256(dv * dv, wred, tid);
    float sd = sqrtf(ss * (1.0f / (NPTS - 1))) + 1e-6f;
    float xsv = dv / sd;
    xs[tid] = xsv;
    if (tid < K_REF) {
        float q = 0.01f + 0.06125f * (float)tid;
        gs[tid] = erfinvf(2.0f * q - 1.0f) * 1.41421356237309504880f;
    }
    __syncthreads();

    float s1a = 0.f, s1b = 0.f;
#pragma unroll 8
    for (int j = 0; j < NPTS; j += 2) {
        float d0 = xsv - xs[j];
        float d1 = xsv - xs[j + 1];
        s1a += EXP2(NEG_HALF_LOG2E * d0 * d0);
        s1b += EXP2(NEG_HALF_LOG2E * d1 * d1);
    }
    float s2 = 0.f;
#pragma unroll
    for (int k = 0; k < K_REF; ++k) {
        float d = xsv - gs[k];
        s2 += EXP2(NEG_HALF_LOG2E * d * d);
    }
    float c = (s1a + s1b) * (1.0f / ((float)NPTS * (float)NPTS))
            - s2 * (2.0f / ((float)NPTS * (float)K_REF));
    float tot = block_sum_256(c, wred, tid);
    if (tid == 0) w[SIG_OFF + zi * NSLICES + m] = tot * (0.5f / (float)NSLICES);
}

// ---------------- final: reduce slots + t3 + combine ------------------------
__global__ __launch_bounds__(256) void final_kernel(const float* __restrict__ w,
                                                    float* __restrict__ out) {
    __shared__ float wred[4];
    const int tid = threadIdx.x;
    float sv = 0.f;
#pragma unroll
    for (int i = tid; i < 2 * NSLICES; i += 256) sv += w[SIG_OFF + i];
    float iv = (tid < 192) ? w[INV_OFF + tid] : 0.f;
    float sig = block_sum_256(sv, wred, tid);
    float inv = block_sum_256(iv, wred, tid);
    if (tid == 0) {
        float g[K_REF];
#pragma unroll
        for (int k = 0; k < K_REF; ++k) {
            float q = 0.01f + 0.06125f * (float)k;
            g[k] = erfinvf(2.0f * q - 1.0f) * 1.41421356237309504880f;
        }
        float t3 = 0.f;
        for (int k = 0; k < K_REF; ++k)
            for (int l = 0; l < K_REF; ++l) {
                float dd = g[k] - g[l];
                t3 += EXP2(NEG_HALF_LOG2E * dd * dd);
            }
        t3 *= (1.0f / ((float)K_REF * (float)K_REF));
        out[0] = 25.0f * inv * (1.0f / ((float)NPTS * (float)DIM))
               + 25.0f * (sig + t3);
    }
}

extern "C" void kernel_launch(void* const* d_in, const int* in_sizes, int n_in,
                              void* d_out, int out_size, void* d_ws, size_t ws_size,
                              hipStream_t stream) {
    const float* za = (const float*)d_in[0];
    const float* zb = (const float*)d_in[1];
    const float* slices = (const float*)d_in[2];
    float* out = (float*)d_out;
    float* w = (float*)d_ws;

    const size_t need_full = (size_t)(XP_OFF + 2 * KSPLIT * XSZ) * sizeof(float); // ~16.8 MB
    const int npart = (ws_size >= need_full) ? KSPLIT : 1;

    if (npart == 1)   // fallback only (ws is 256 MiB in this harness; never taken)
        hipMemsetAsync(w + XP_OFF, 0, (size_t)2 * XSZ * sizeof(float), stream);

    inv_kernel<<<192, 256, 0, stream>>>(za, zb, w);
    dim3 pg(4, 16, 2 * KSPLIT);
    proj_kernel<<<pg, 256, 0, stream>>>(za, zb, slices, w, npart);
    dim3 sg(NSLICES, 2);
    sigreg_kernel<<<sg, 256, 0, stream>>>(w, npart);
    final_kernel<<<1, 256, 0, stream>>>(w, out);
}

// Round 4
// 96.575 us; speedup vs baseline: 1.6528x; 1.1462x over previous
//
#include <hip/hip_runtime.h>
#include <hip/hip_bf16.h>
#include <math.h>

#define NSLICES 1024
#define DIM     768
#define NPTS    256
#define K_REF   17
#define KSPLIT  8
#define KCHUNK  (DIM / KSPLIT)      // 96
#define XSZ     (NSLICES * NPTS)    // 262144 floats per (z, kchunk) partial

// ws float layout — every slot is fully rewritten every call (no zero-init needed)
#define INV_OFF 0                   // 192 partials
#define G_OFF   208                 // 17 scaled reference points
#define SIG_OFF 256                 // 2048 partials
#define XP_OFF  2560                // projection partials

#define EXP2(x) __builtin_amdgcn_exp2f(x)
// y = x * SCALE_A  =>  exp(-0.5(xi-xj)^2) == exp2(-(yi-yj)^2)
#define SCALE_A 0.84932180028801904272f      // sqrt(0.5 * log2(e))
#define INV_N2  1.52587890625e-05f           // 1/256^2
#define T2_SC   4.595588235294118e-4f        // 2/(256*17)

__device__ __forceinline__ float wave_sum(float v) {
#pragma unroll
    for (int o = 32; o; o >>= 1) v += __shfl_xor(v, o, 64);
    return v;
}

__device__ __forceinline__ float block_sum_256(float v, float* wred, int tid) {
    v = wave_sum(v);
    if ((tid & 63) == 0) wred[tid >> 6] = v;
    __syncthreads();
    float r = wred[0] + wred[1] + wred[2] + wred[3];
    __syncthreads();
    return r;
}

// ---------------- inv_loss partials + scaled reference points ---------------
__global__ __launch_bounds__(256) void inv_kernel(const float* __restrict__ za,
                                                  const float* __restrict__ zb,
                                                  float* __restrict__ w) {
    __shared__ float wred[4];
    int tid = threadIdx.x;
    int idx = blockIdx.x * 256 + tid;           // 192 blocks * 256 = 49152 float4s exactly
    const float4* A = (const float4*)za;
    const float4* B = (const float4*)zb;
    float4 a = A[idx], b = B[idx];
    float dx = a.x - b.x, dy = a.y - b.y, dz = a.z - b.z, dw = a.w - b.w;
    float p = dx * dx + dy * dy + dz * dz + dw * dw;
    float s = block_sum_256(p, wred, tid);
    if (tid == 0) w[INV_OFF + blockIdx.x] = s;
    if (blockIdx.x == 0 && tid < K_REF) {
        float q = 0.01f + 0.06125f * (float)tid;
        w[G_OFF + tid] = erfinvf(2.0f * q - 1.0f) * 1.41421356237309504880f * SCALE_A;
    }
}

// ---------------- projection GEMM: x[m][n] = dot(slices[m], z[n]) -----------
// (slice normalization dropped: standardization is scale-invariant per slice)
// grid: (4 n-tiles, 16 m-tiles, 2 z * KSPLIT k-chunks), block 256 = 16x16, 4x4/thread.
__global__ __launch_bounds__(256) void proj_kernel(const float* __restrict__ za,
                                                   const float* __restrict__ zb,
                                                   const float* __restrict__ slices,
                                                   float* __restrict__ w, int npart) {
    __shared__ float sA[16][68];
    __shared__ float sB[16][68];
    const int nt = blockIdx.x;            // 0..3
    const int mt = blockIdx.y;            // 0..15
    const int zi = blockIdx.z >> 3;       // 0..1
    const int kc = blockIdx.z & 7;        // 0..7
    const float* Z = zi ? zb : za;
    const int m0 = mt * 64, n0 = nt * 64;
    const int tid = threadIdx.x;
    const int tx = tid & 15, ty = tid >> 4;
    const int lr = tid >> 2, lq = tid & 3;      // loader: row 0..63, quad 0..3
    const int kbase = kc * KCHUNK;

    float acc[4][4] = {};

    for (int k0 = 0; k0 < KCHUNK; k0 += 16) {
        float4 av = *(const float4*)(slices + (size_t)(m0 + lr) * DIM + kbase + k0 + lq * 4);
        float4 bv = *(const float4*)(Z + (size_t)(n0 + lr) * DIM + kbase + k0 + lq * 4);
        // transposed store: sA[kk][m]
        sA[lq * 4 + 0][lr] = av.x; sA[lq * 4 + 1][lr] = av.y;
        sA[lq * 4 + 2][lr] = av.z; sA[lq * 4 + 3][lr] = av.w;
        sB[lq * 4 + 0][lr] = bv.x; sB[lq * 4 + 1][lr] = bv.y;
        sB[lq * 4 + 2][lr] = bv.z; sB[lq * 4 + 3][lr] = bv.w;
        __syncthreads();
#pragma unroll
        for (int kk = 0; kk < 16; ++kk) {
            float4 a = *(const float4*)&sA[kk][ty * 4];
            float4 b = *(const float4*)&sB[kk][tx * 4];
            acc[0][0] += a.x * b.x; acc[0][1] += a.x * b.y; acc[0][2] += a.x * b.z; acc[0][3] += a.x * b.w;
            acc[1][0] += a.y * b.x; acc[1][1] += a.y * b.y; acc[1][2] += a.y * b.z; acc[1][3] += a.y * b.w;
            acc[2][0] += a.z * b.x; acc[2][1] += a.z * b.y; acc[2][2] += a.z * b.z; acc[2][3] += a.z * b.w;
            acc[3][0] += a.w * b.x; acc[3][1] += a.w * b.y; acc[3][2] += a.w * b.z; acc[3][3] += a.w * b.w;
        }
        __syncthreads();
    }

    if (npart == KSPLIT) {
        float* X = w + XP_OFF + ((size_t)zi * KSPLIT + kc) * XSZ;
#pragma unroll
        for (int i = 0; i < 4; ++i) {
            float4 o; o.x = acc[i][0]; o.y = acc[i][1]; o.z = acc[i][2]; o.w = acc[i][3];
            *(float4*)(X + (size_t)(m0 + ty * 4 + i) * NPTS + n0 + tx * 4) = o;
        }
    } else {
        float* X = w + XP_OFF + (size_t)zi * XSZ;
#pragma unroll
        for (int i = 0; i < 4; ++i)
#pragma unroll
            for (int j = 0; j < 4; ++j)
                atomicAdd(X + (size_t)(m0 + ty * 4 + i) * NPTS + n0 + tx * 4 + j, acc[i][j]);
    }
}

// ---------------- per-slice sigreg (t1 + t2), symmetric-halved --------------
// t1 off-diagonal: sum over circular offsets o=1..128 of S_o; total = 2*s1 - s128.
// grid: (NSLICES, 2); block 256 (one thread per sample point).
__global__ __launch_bounds__(256) void sigreg_kernel(float* __restrict__ w, int npart) {
    __shared__ float ys[2 * NPTS];     // duplicated so reads are base + imm offset
    __shared__ float gsh[K_REF];
    __shared__ float wred[4];
    const int m = blockIdx.x;
    const int zi = blockIdx.y;
    const int tid = threadIdx.x;

    const float* Xb = w + XP_OFF + (size_t)zi * npart * XSZ + (size_t)m * NPTS + tid;
    float xv = 0.f;
    for (int p = 0; p < npart; ++p) xv += Xb[(size_t)p * XSZ];
    if (tid < K_REF) gsh[tid] = w[G_OFF + tid];

    float mu = block_sum_256(xv, wred, tid) * (1.0f / NPTS);
    float dv = xv - mu;
    float ss = block_sum_256(dv * dv, wred, tid);
    float sd = sqrtf(ss * (1.0f / (NPTS - 1))) + 1e-6f;
    float yv = (dv / sd) * SCALE_A;
    ys[tid] = yv;
    ys[tid + NPTS] = yv;
    __syncthreads();

    float s1a = 0.f, s1b = 0.f;
#pragma unroll 8
    for (int o = 1; o <= 128; o += 2) {
        float d0 = yv - ys[tid + o];
        float d1 = yv - ys[tid + o + 1];
        s1a += EXP2(-(d0 * d0));
        s1b += EXP2(-(d1 * d1));
    }
    float d128 = yv - ys[tid + 128];
    float s128 = EXP2(-(d128 * d128));
    float s2 = 0.f;
#pragma unroll
    for (int k = 0; k < K_REF; ++k) {
        float d = yv - gsh[k];
        s2 += EXP2(-(d * d));
    }
    // off-diag = 2*(s1 incl o=128) - s128 ; diagonal N added at tid 0
    float c = (2.0f * (s1a + s1b) - s128) * INV_N2 - s2 * T2_SC;
    if (tid == 0) c += (float)NPTS * INV_N2;
    float tot = block_sum_256(c, wred, tid);
    if (tid == 0) w[SIG_OFF + zi * NSLICES + m] = tot * (0.5f / (float)NSLICES);
}

// ---------------- final: reduce slots + t3 + combine ------------------------
__global__ __launch_bounds__(256) void final_kernel(const float* __restrict__ w,
                                                    float* __restrict__ out) {
    __shared__ float wred[4];
    __shared__ float gsh[K_REF];
    const int tid = threadIdx.x;
    if (tid < K_REF) gsh[tid] = w[G_OFF + tid];
    float sv = 0.f;
    for (int i = tid; i < 2 * NSLICES; i += 256) sv += w[SIG_OFF + i];
    float iv = (tid < 192) ? w[INV_OFF + tid] : 0.f;
    float sig = block_sum_256(sv, wred, tid);
    float inv = block_sum_256(iv, wred, tid);
    // t3 over 289 pairs, parallel (gsh already scaled by SCALE_A)
    float t3p = 0.f;
    for (int idx = tid; idx < K_REF * K_REF; idx += 256) {
        int k = idx / K_REF, l = idx - k * K_REF;
        float d = gsh[k] - gsh[l];
        t3p += EXP2(-(d * d));
    }
    float t3 = block_sum_256(t3p, wred, tid) * (1.0f / ((float)K_REF * (float)K_REF));
    if (tid == 0) {
        out[0] = 25.0f * inv * (1.0f / ((float)NPTS * (float)DIM))
               + 25.0f * (sig + t3);
    }
}

extern "C" void kernel_launch(void* const* d_in, const int* in_sizes, int n_in,
                              void* d_out, int out_size, void* d_ws, size_t ws_size,
                              hipStream_t stream) {
    const float* za = (const float*)d_in[0];
    const float* zb = (const float*)d_in[1];
    const float* slices = (const float*)d_in[2];
    float* out = (float*)d_out;
    float* w = (float*)d_ws;

    const size_t need_full = (size_t)(XP_OFF + 2 * KSPLIT * XSZ) * sizeof(float); // ~16.8 MB
    const int npart = (ws_size >= need_full) ? KSPLIT : 1;

    if (npart == 1)   // fallback only (ws is plenty in this harness; never taken)
        hipMemsetAsync(w + XP_OFF, 0, (size_t)2 * XSZ * sizeof(float), stream);

    inv_kernel<<<192, 256, 0, stream>>>(za, zb, w);
    dim3 pg(4, 16, 2 * KSPLIT);
    proj_kernel<<<pg, 256, 0, stream>>>(za, zb, slices, w, npart);
    dim3 sg(NSLICES, 2);
    sigreg_kernel<<<sg, 256, 0, stream>>>(w, npart);
    final_kernel<<<1, 256, 0, stream>>>(w, out);
}